// Round 21
// baseline (297.207 us; speedup 1.0000x reference)
//
#include <hip/hip_runtime.h>
#include <hip/hip_bf16.h>

#define DEV __device__ __forceinline__

#define B_    16
#define T_    40
#define TDEC  41
#define NH    128
#define HF    8
#define WF    128
#define HID   64
#define G3    192
#define NCLS  6625
#define SPAT  1024
#define NFRAG 415          // ceil(6625/16)

typedef _Float16 half8 __attribute__((ext_vector_type(8)));
typedef _Float16 half2_ __attribute__((ext_vector_type(2)));
typedef float    f32x4 __attribute__((ext_vector_type(4)));
typedef float    f32x2 __attribute__((ext_vector_type(2)));

#if __has_builtin(__builtin_amdgcn_fdot2)
#define FDOT2(w,h,acc) __builtin_amdgcn_fdot2((w),(h),(acc),false)
#else
#define FDOT2(w,h,acc) ((acc) + (float)((w)[0])*(float)((h)[0]) + (float)((w)[1])*(float)((h)[1]))
#endif

DEV float sigmoidf_(float x){ return 1.0f/(1.0f + __expf(-x)); }
DEV float tanhf_(float x){ float e = __expf(2.0f*x); return 1.0f - 2.0f/(e + 1.0f); }
DEV float gelu_(float x){ return 0.5f*x*(1.0f + erff(x*0.70710678118654752f)); }
DEV float bnf_(float x, float g, float b, float m, float v){
  return (x - m)*rsqrtf(v + 1e-5f)*g + b;
}

// scan step macro (locals: w0q/w1q/w2q, b0..b2, hg, hsh16, xpb, x0a..x2c, outp, b, g)
#define SCAN_LOOP(STEPS, WRITE_ALL)                                            \
  for (int t = 0; t < (STEPS); ++t){                                           \
    float x0c = 0.f, x1c = 0.f, x2c = 0.f;                                     \
    if (t + 2 < (STEPS)){                                                      \
      const float* p = xpb + (t + 2)*G3 + g;                                   \
      x0c = p[0]; x1c = p[HID]; x2c = p[2*HID];                                \
    }                                                                          \
    const uint4* h4 = (const uint4*)hsh16;                                     \
    float a0 = b0, a1 = b1, a2 = b2;                                           \
    float d0 = 0.f, d1 = 0.f, d2 = 0.f;                                        \
    _Pragma("unroll")                                                          \
    for (int i = 0; i < 8; i += 2){                                            \
      uint4 hvA = h4[i], hvB = h4[i+1];                                        \
      DO4(hvA, i,   a0, a1, a2)                                                \
      DO4(hvB, i+1, d0, d1, d2)                                                \
    }                                                                          \
    float hp0 = a0 + d0;                                                       \
    float hp1 = a1 + d1;                                                       \
    float hp2 = a2 + d2;                                                       \
    float e0 = __expf(-(x0a + hp0));                                           \
    float r  = __builtin_amdgcn_rcpf(1.0f + e0);                               \
    float e1 = __expf(-(x1a + hp1));                                           \
    float z  = __builtin_amdgcn_rcpf(1.0f + e1);                               \
    float ag = x2a + r*hp2;                                                    \
    float ex = __expf(2.0f*ag);                                                \
    float n  = 1.0f - 2.0f*__builtin_amdgcn_rcpf(ex + 1.0f);                   \
    hg = z*(hg - n) + n;                                                       \
    if (WRITE_ALL) outp[(b*TDEC + t)*HID + g] = hg;                            \
    hsh16[g] = (_Float16)hg;                                                   \
    x0a = x0b; x1a = x1b; x2a = x2b;                                           \
    x0b = x0c; x1b = x1c; x2b = x2c;                                           \
  }

#define DO4(hv, wq, aa, bb, cc)                                                \
  { half2_ h0 = __builtin_bit_cast(half2_, hv.x);                              \
    half2_ h1 = __builtin_bit_cast(half2_, hv.y);                              \
    half2_ h2 = __builtin_bit_cast(half2_, hv.z);                              \
    half2_ h3 = __builtin_bit_cast(half2_, hv.w);                              \
    aa = FDOT2(__builtin_bit_cast(half2_, w0q[wq].x), h0, aa);                 \
    bb = FDOT2(__builtin_bit_cast(half2_, w1q[wq].x), h0, bb);                 \
    cc = FDOT2(__builtin_bit_cast(half2_, w2q[wq].x), h0, cc);                 \
    aa = FDOT2(__builtin_bit_cast(half2_, w0q[wq].y), h1, aa);                 \
    bb = FDOT2(__builtin_bit_cast(half2_, w1q[wq].y), h1, bb);                 \
    cc = FDOT2(__builtin_bit_cast(half2_, w2q[wq].y), h1, cc);                 \
    aa = FDOT2(__builtin_bit_cast(half2_, w0q[wq].z), h2, aa);                 \
    bb = FDOT2(__builtin_bit_cast(half2_, w1q[wq].z), h2, bb);                 \
    cc = FDOT2(__builtin_bit_cast(half2_, w2q[wq].z), h2, cc);                 \
    aa = FDOT2(__builtin_bit_cast(half2_, w0q[wq].w), h3, aa);                 \
    bb = FDOT2(__builtin_bit_cast(half2_, w1q[wq].w), h3, bb);                 \
    cc = FDOT2(__builtin_bit_cast(half2_, w2q[wq].w), h3, cc); }

// ---------------- FRONT: conv0 | misc preps | fcprep (merged, independent) ---
__global__ __launch_bounds__(256) void k_front(
    const float* __restrict__ x, const float* __restrict__ w,
    const float* __restrict__ bias, const float* __restrict__ bng,
    const float* __restrict__ bnb, const float* __restrict__ bnm,
    const float* __restrict__ bnv, float* __restrict__ h,
    const float* __restrict__ pw, float* __restrict__ pwT,
    const float* __restrict__ kw, _Float16* __restrict__ kwA,
    const int* __restrict__ tgt, const float* __restrict__ emb,
    float* __restrict__ indec,
    const float* __restrict__ encwhh, unsigned* __restrict__ enc16,
    const float* __restrict__ decwhh, unsigned* __restrict__ dec16,
    const float* __restrict__ wih, _Float16* __restrict__ wihH,
    _Float16* __restrict__ wihL,
    const float* __restrict__ fcw, _Float16* __restrict__ fcwH,
    _Float16* __restrict__ fcwL)
{
  int bid = blockIdx.x;
  if (bid < 2048){
    int tid = bid*256 + threadIdx.x;
    int ow = tid & 127;
    int oh = (tid >> 7) & 7;
    int c4 = (tid >> 10) & 31;
    int b  = tid >> 15;
    float acc[4] = {0.f,0.f,0.f,0.f};
    int xbase = ((b*3)*32 + oh*4)*512 + ow*4;
    for (int ci = 0; ci < 3; ++ci){
      #pragma unroll
      for (int kh = 0; kh < 4; ++kh){
        float4 xv = *(const float4*)(x + xbase + ci*(32*512) + kh*512);
        #pragma unroll
        for (int cc = 0; cc < 4; ++cc){
          int co = c4*4 + cc;
          const float* wp = w + ((co*3 + ci)*4 + kh)*4;
          acc[cc] += xv.x*wp[0] + xv.y*wp[1] + xv.z*wp[2] + xv.w*wp[3];
        }
      }
    }
    #pragma unroll
    for (int cc = 0; cc < 4; ++cc){
      int co = c4*4 + cc;
      float v = acc[cc] + bias[co];
      v = bnf_(v, bng[co], bnb[co], bnm[co], bnv[co]);
      h[((b*NH + co)*HF + oh)*WF + ow] = gelu_(v);
    }
  } else if (bid < 3664){
    int mbid = bid - 2048;
    if (mbid < 64){
      int tid = mbid*256 + threadIdx.x;      // 16384
      int ci = tid & 127; int co = tid >> 7;
      pwT[ci*128 + co] = pw[16384 + co*128 + ci];
    } else if (mbid < 640){
      int tid = (mbid - 64)*256 + threadIdx.x;   // 147456
      int j = tid & 7;
      int l = (tid >> 3) & 63;
      int f = (tid >> 9) & 7;
      int s = tid >> 12;
      int co = f*16 + (l & 15);
      int k  = s*32 + ((l >> 4) << 3) + j;
      int r  = k >> 7;
      int ci = k & 127;
      kwA[tid] = (_Float16)kw[(co*128 + ci)*9 + r];
    } else if (mbid < 800){
      int tid = (mbid - 640)*256 + threadIdx.x;  // 40960
      if (tid >= B_*T_*HID) return;
      int j = tid & 63; int rest = tid >> 6;
      int t = rest % T_; int b = rest / T_;
      int cls = tgt[b*T_ + t];
      indec[(b*TDEC + 1 + t)*HID + j] = emb[cls*HID + j];
    } else if (mbid < 848){
      int seg = mbid - 800;                      // 0..47 (24 enc, 24 dec)
      const float* src = (seg < 24) ? encwhh : decwhh;
      unsigned* dst    = (seg < 24) ? enc16   : dec16;
      int tid = (seg % 24)*256 + threadIdx.x;   // 6144
      int r = tid >> 5; int k2 = tid & 31;
      half2_ hv;
      hv[0] = (_Float16)src[r*HID + 2*k2];
      hv[1] = (_Float16)src[r*HID + 2*k2 + 1];
      dst[tid] = __builtin_bit_cast(unsigned, hv);
    } else {
      int tid = (mbid - 848)*256 + threadIdx.x;  // 196608
      if (tid >= 12*32*64*8) return;
      int j  = tid & 7;
      int l  = (tid >> 3) & 63;
      int kf = (tid >> 9) & 31;
      int nf = tid >> 14;
      int n = nf*16 + (l & 15);
      int k = kf*32 + ((l >> 4) << 3) + j;
      float v = wih[n*1024 + k];
      _Float16 hi = (_Float16)v;
      wihH[tid] = hi;
      wihL[tid] = (_Float16)(v - (float)hi);
    }
  } else {
    int tid = (bid - 3664)*256 + threadIdx.x;   // 849920
    if (tid >= NFRAG*4*64*8) return;
    int j  = tid & 7;
    int l  = (tid >> 3) & 63;
    int kf = (tid >> 9) & 3;
    int nf = tid >> 11;
    int n = nf*16 + (l & 15);
    int k = kf*32 + ((l >> 4) << 3) + j;
    float v = (n < NCLS) ? fcw[n*NH + k] : 0.f;
    _Float16 hi = (_Float16)v;
    fcwH[tid] = hi;
    fcwL[tid] = (_Float16)(v - (float)hi);
  }
}

// ---------------- depthwise 3x3 (blk idx 1) + BN + GELU + residual -> t -------
__global__ __launch_bounds__(256) void k_dw(const float* __restrict__ h,
    const float* __restrict__ dww, const float* __restrict__ dwb,
    const float* __restrict__ g1, const float* __restrict__ b1,
    const float* __restrict__ m1, const float* __restrict__ v1,
    float* __restrict__ t)
{
  int tid = blockIdx.x*256 + threadIdx.x;   // 2097152
  int ow = tid & 127;
  int oh = (tid >> 7) & 7;
  int c  = (tid >> 10) & 127;
  int b  = tid >> 17;
  const float* wp = dww + NH*9 + c*9;       // block index 1
  const float* hp = h + ((b*NH + c)*HF)*WF;
  float acc = 0.f;
  #pragma unroll
  for (int kh = 0; kh < 3; ++kh){
    int ih = oh + kh - 1;
    if (ih < 0 || ih >= HF) continue;
    #pragma unroll
    for (int kw = 0; kw < 3; ++kw){
      int iw = ow + kw - 1;
      if (iw < 0 || iw >= WF) continue;
      acc += hp[ih*WF + iw]*wp[kh*3 + kw];
    }
  }
  float val = acc + dwb[NH + c];
  val = bnf_(val, g1[NH + c], b1[NH + c], m1[NH + c], v1[NH + c]);
  t[tid] = hp[oh*WF + ow] + gelu_(val);
}

// ---------------- pointwise 128x128 (blk idx 1) + BN + GELU -> feat ----------
__global__ __launch_bounds__(512) void k_pw(const float* __restrict__ t,
    const float* __restrict__ pwT, const float* __restrict__ pwb,
    const float* __restrict__ g2, const float* __restrict__ b2,
    const float* __restrict__ m2, const float* __restrict__ v2,
    float* __restrict__ feat)
{
  int bid = blockIdx.x;                     // (b, oh, whalf): 256 blocks
  int wh = bid & 1; int oh = (bid >> 1) & 7; int b = bid >> 4;
  int w0 = wh*64;
  int tid = threadIdx.x;
  __shared__ __align__(16) float tile[128*64];
  for (int i = 0; i < 16; ++i){
    int e = i*512 + tid; int ci = e >> 6; int wloc = e & 63;
    tile[ci*64 + wloc] = t[((b*NH + ci)*HF + oh)*WF + w0 + wloc];
  }
  __syncthreads();
  int co = tid & 127; int wq = tid >> 7;
  float acc[16];
  #pragma unroll
  for (int i = 0; i < 16; ++i) acc[i] = 0.f;
  for (int ci = 0; ci < 128; ++ci){
    float wt = pwT[ci*128 + co];
    const float4* tp = (const float4*)(tile + ci*64 + wq*16);
    #pragma unroll
    for (int j = 0; j < 4; ++j){
      float4 tv = tp[j];
      acc[j*4+0] += tv.x*wt; acc[j*4+1] += tv.y*wt;
      acc[j*4+2] += tv.z*wt; acc[j*4+3] += tv.w*wt;
    }
  }
  float bb = pwb[128 + co];
  float gg = g2[128 + co], bc = b2[128 + co], mm = m2[128 + co], vv = v2[128 + co];
  float* op = feat + ((b*NH + co)*HF + oh)*WF + w0 + wq*16;
  #pragma unroll
  for (int i = 0; i < 16; ++i){
    float v = bnf_(acc[i] + bb, gg, bc, mm, vv);
    op[i] = gelu_(v);
  }
}

// ---------------- enc xp via split-fp16 MFMA, 512 waves ----------------------
__global__ __launch_bounds__(64) void k_encxp3(const float* __restrict__ feat,
    const uint4* __restrict__ wihH, const uint4* __restrict__ wihL,
    const float* __restrict__ bih, float* __restrict__ xp)
{
  int bid = blockIdx.x;
  int mf = bid & 127;              // b = mf>>3, w-chunk = mf&7
  int ny = bid >> 7;               // 0..3 -> nf = ny*3 + {0,1,2}
  int l  = threadIdx.x;
  int b  = mf >> 3, wc = mf & 7;
  int m_w = wc*16 + (l & 15);
  f32x4 acc0{0.f,0.f,0.f,0.f}, acc1{0.f,0.f,0.f,0.f}, acc2{0.f,0.f,0.f,0.f};
  int nf0 = ny*3;
  for (int kf = 0; kf < 32; ++kf){
    int ci = kf*4 + (l >> 4);
    const float* ap = feat + ((b*NH + ci)*HF)*WF + m_w;
    float av[8];
    #pragma unroll
    for (int j = 0; j < 8; ++j) av[j] = ap[j*WF];
    half8 ah, al;
    #pragma unroll
    for (int j = 0; j < 8; ++j){
      ah[j] = (_Float16)av[j];
      al[j] = (_Float16)(av[j] - (float)ah[j]);
    }
    uint4 bH0 = wihH[((nf0+0)*32 + kf)*64 + l];
    uint4 bL0 = wihL[((nf0+0)*32 + kf)*64 + l];
    uint4 bH1 = wihH[((nf0+1)*32 + kf)*64 + l];
    uint4 bL1 = wihL[((nf0+1)*32 + kf)*64 + l];
    uint4 bH2 = wihH[((nf0+2)*32 + kf)*64 + l];
    uint4 bL2 = wihL[((nf0+2)*32 + kf)*64 + l];
    #define ACCUM(accv, bH, bL) {                                              \
      half8 wh = __builtin_bit_cast(half8, bH);                                \
      half8 wl = __builtin_bit_cast(half8, bL);                                \
      accv = __builtin_amdgcn_mfma_f32_16x16x32_f16(ah, wh, accv, 0, 0, 0);    \
      accv = __builtin_amdgcn_mfma_f32_16x16x32_f16(al, wh, accv, 0, 0, 0);    \
      accv = __builtin_amdgcn_mfma_f32_16x16x32_f16(ah, wl, accv, 0, 0, 0);    \
    }
    ACCUM(acc0, bH0, bL0)
    ACCUM(acc1, bH1, bL1)
    ACCUM(acc2, bH2, bL2)
    #undef ACCUM
  }
  int mbase = b*WF + wc*16 + ((l >> 4) << 2);
  #pragma unroll
  for (int i = 0; i < 3; ++i){
    f32x4 a = (i == 0) ? acc0 : (i == 1) ? acc1 : acc2;
    int n = (nf0 + i)*16 + (l & 15);
    float bias = bih[n];
    #pragma unroll
    for (int q = 0; q < 4; ++q)
      xp[(mbase + q)*G3 + n] = a[q] + bias;
  }
}

// ---------------- standalone dec scan (fp16 weights + fdot2) -----------------
template<int STEPS, bool WRITE_ALL>
__global__ __attribute__((amdgpu_waves_per_eu(1, 1))) __launch_bounds__(64)
void k_scan2(const float* __restrict__ xp, const uint4* __restrict__ whh16,
             const float* __restrict__ bhh, float* __restrict__ outp)
{
  __shared__ __align__(16) _Float16 hsh16[HID];
  int g = threadIdx.x;
  int b = blockIdx.x;
  uint4 w0q[8], w1q[8], w2q[8];
  const uint4* q0 = whh16 + g*8;
  const uint4* q1 = whh16 + (HID + g)*8;
  const uint4* q2 = whh16 + (2*HID + g)*8;
  #pragma unroll
  for (int k = 0; k < 8; ++k){ w0q[k] = q0[k]; w1q[k] = q1[k]; w2q[k] = q2[k]; }
  float b0 = bhh[g], b1 = bhh[HID + g], b2 = bhh[2*HID + g];
  float hg = 0.f;
  hsh16[g] = (_Float16)0.f;
  const float* xpb = xp + b*STEPS*G3;
  float x0a = xpb[g], x1a = xpb[HID + g], x2a = xpb[2*HID + g];
  float x0b = 0.f, x1b = 0.f, x2b = 0.f;
  if (STEPS > 1){
    const float* p = xpb + G3 + g;
    x0b = p[0]; x1b = p[HID]; x2b = p[2*HID];
  }
  SCAN_LOOP(STEPS, WRITE_ALL)
  if (!WRITE_ALL) outp[(b*TDEC)*HID + g] = hg;
}

// ---------------- MERGED: enc scan (blocks 0-15) + kconv (16-1039) -----------
// Conv widened to 4 m-frags/block: kwA re-reads /4 (A L2 traffic 600->150MB),
// conv waves/CU 16->4 (less scan interference). B traffic unchanged.
__global__ __launch_bounds__(64) void k_escan_conv(
    const float* __restrict__ xp, const uint4* __restrict__ whh16,
    const float* __restrict__ bhh, float* __restrict__ outp,
    const float* __restrict__ feat, const uint4* __restrict__ kwA4,
    const float* __restrict__ kb, float* __restrict__ ko)
{
  __shared__ __align__(16) _Float16 hsh16[HID];
  int bigid = blockIdx.x;
  if (bigid < 16){
    __builtin_amdgcn_s_setprio(3);
    int g = threadIdx.x;
    int b = bigid;
    uint4 w0q[8], w1q[8], w2q[8];
    const uint4* q0 = whh16 + g*8;
    const uint4* q1 = whh16 + (HID + g)*8;
    const uint4* q2 = whh16 + (2*HID + g)*8;
    #pragma unroll
    for (int k = 0; k < 8; ++k){ w0q[k] = q0[k]; w1q[k] = q1[k]; w2q[k] = q2[k]; }
    float b0 = bhh[g], b1 = bhh[HID + g], b2 = bhh[2*HID + g];
    float hg = 0.f;
    hsh16[g] = (_Float16)0.f;
    const float* xpb = xp + b*WF*G3;
    float x0a = xpb[g], x1a = xpb[HID + g], x2a = xpb[2*HID + g];
    float x0b = 0.f, x1b = 0.f, x2b = 0.f;
    {
      const float* p = xpb + G3 + g;
      x0b = p[0]; x1b = p[HID]; x2b = p[2*HID];
    }
    SCAN_LOOP(WF, false)
    outp[(b*TDEC)*HID + g] = hg;
    __builtin_amdgcn_s_setprio(0);
    return;
  }
  int bid = bigid - 16;                 // 1024 conv blocks
  int b  = ((bid & 7) << 1) | ((bid >> 3) & 1);   // XCD-aware batch pair
  int cs = (bid >> 4) & 3;
  int wq = (bid >> 6) & 1;
  int oh = (bid >> 7) & 7;
  int l  = threadIdx.x;
  int cib = (l >> 4) << 3;

  f32x4 acc[2][4];
  #pragma unroll
  for (int cf = 0; cf < 2; ++cf)
    #pragma unroll
    for (int mm = 0; mm < 4; ++mm)
      acc[cf][mm] = (f32x4){0.f,0.f,0.f,0.f};

  uint4 a0A, a0B, a1A, a1B;
  float bvA[4][8], bvB[4][8];

  #define ISS(s, aX, aY, bvv) {                                               \
    aX = kwA4[(s)*512 + cs*128 + l];                                          \
    aY = kwA4[(s)*512 + cs*128 + 64 + l];                                     \
    int r = (s) >> 2; int dh = r/3 - 1; int dw2 = r%3 - 1;                    \
    int ci0 = ((s) & 3) << 5;                                                 \
    int ih = oh + dh;                                                         \
    bool okh = (ih >= 0) & (ih < HF);                                         \
    const float* fpb = feat + ((b*NH + ci0 + cib)*HF + ih)*WF;                \
    _Pragma("unroll")                                                         \
    for (int mm = 0; mm < 4; ++mm){                                           \
      int iw = wq*64 + mm*16 + (l & 15) + dw2;                                \
      bool ok = okh & (iw >= 0) & (iw < WF);                                  \
      _Pragma("unroll")                                                       \
      for (int jj = 0; jj < 8; ++jj)                                          \
        bvv[mm][jj] = ok ? fpb[jj*(HF*WF) + iw] : 0.f;                        \
    }                                                                         \
  }
  #define CMP(aX, aY, bvv) {                                                  \
    half8 af0 = __builtin_bit_cast(half8, aX);                                \
    half8 af1 = __builtin_bit_cast(half8, aY);                                \
    _Pragma("unroll")                                                         \
    for (int mm = 0; mm < 4; ++mm){                                           \
      half8 bf;                                                               \
      _Pragma("unroll")                                                       \
      for (int jj = 0; jj < 8; ++jj) bf[jj] = (_Float16)bvv[mm][jj];          \
      acc[0][mm] = __builtin_amdgcn_mfma_f32_16x16x32_f16(af0, bf, acc[0][mm], 0, 0, 0); \
      acc[1][mm] = __builtin_amdgcn_mfma_f32_16x16x32_f16(af1, bf, acc[1][mm], 0, 0, 0); \
    }                                                                         \
  }

  ISS(0, a0A, a0B, bvA);
  for (int s = 0; s < 36; s += 2){
    if (s + 1 < 36) ISS(s + 1, a1A, a1B, bvB);
    CMP(a0A, a0B, bvA);
    if (s + 2 < 36) ISS(s + 2, a0A, a0B, bvA);
    if (s + 1 < 36) CMP(a1A, a1B, bvB);
  }
  #undef ISS
  #undef CMP

  #pragma unroll
  for (int mm = 0; mm < 4; ++mm){
    int m = wq*64 + mm*16 + (l & 15);
    #pragma unroll
    for (int q = 0; q < 4; ++q){
      int co0 = cs*32 + ((l >> 4) << 2) + q;
      int co1 = co0 + 16;
      ko[((b*NH + co0)*HF + oh)*WF + m] = acc[0][mm][q] + kb[co0];
      ko[((b*NH + co1)*HF + oh)*WF + m] = acc[1][mm][q] + kb[co1];
    }
  }
}

// ---------------- dec xp: (656x64)@(192x64)^T + bih --------------------------
__global__ void k_xpd(const float* __restrict__ indec, const float* __restrict__ wih,
                      const float* __restrict__ bih, float* __restrict__ xpd)
{
  int tid = blockIdx.x*256 + threadIdx.x;   // 125952
  if (tid >= B_*TDEC*G3) return;
  int g = tid % G3; int bt = tid / G3;
  const float4* r4 = (const float4*)(indec + bt*HID);
  const float4* w4 = (const float4*)(wih + g*HID);
  float acc = bih[g];
  #pragma unroll
  for (int j = 0; j < 16; ++j){
    float4 rv = r4[j], wv = w4[j];
    acc += rv.x*wv.x + rv.y*wv.y + rv.z*wv.z + rv.w*wv.w;
  }
  xpd[tid] = acc;
}

// ---------------- q = y @ q_w^T + q_b ---------------------------------------
__global__ void k_q(const float* __restrict__ y, const float* __restrict__ qw,
                    const float* __restrict__ qb0, float* __restrict__ q)
{
  int tid = blockIdx.x*256 + threadIdx.x;   // 83968
  if (tid >= B_*TDEC*NH) return;
  int co = tid & 127; int bt = tid >> 7;
  const float4* r4 = (const float4*)(y + bt*HID);
  const float4* w4 = (const float4*)(qw + co*HID);
  float acc = qb0[co];
  #pragma unroll
  for (int j = 0; j < 16; ++j){
    float4 rv = r4[j], wv = w4[j];
    acc += rv.x*wv.x + rv.y*wv.y + rv.z*wv.z + rv.w*wv.w;
  }
  q[tid] = acc;
}

// ---------------- e[b,t,s]: c-outer/t-inner, kv read once per c --------------
__global__ __launch_bounds__(512) void k_e3(const float* __restrict__ k,
    const float* __restrict__ q, const float* __restrict__ ew,
    const float* __restrict__ eb, float* __restrict__ e)
{
  int bid = blockIdx.x;                 // 256 blocks: (b, st)
  int st = bid & 15; int b = bid >> 4;
  int s0 = st*64;
  int tid = threadIdx.x;
  __shared__ float ksh[NH*64];          // 32 KB: k[b, c, s0..s0+63]
  __shared__ float qsh[TDEC*NH];        // 21 KB: q[b, :, :]
  __shared__ float ewsh[NH];
  #pragma unroll
  for (int i = 0; i < 16; ++i){
    int e2 = i*512 + tid; int c = e2 >> 6; int j = e2 & 63;
    ksh[e2] = k[(b*NH + c)*SPAT + s0 + j];
  }
  #pragma unroll
  for (int i = 0; i < 11; ++i){
    int e2 = i*512 + tid;
    if (e2 < TDEC*NH) qsh[e2] = q[b*TDEC*NH + e2];
  }
  if (tid < NH) ewsh[tid] = ew[tid];
  __syncthreads();
  int sl = tid & 63; int tp = tid >> 6;   // 8 t-groups
  float ebv = eb[0];
  float acc[6] = {ebv, ebv, ebv, ebv, ebv, ebv};
  #pragma unroll 2
  for (int c = 0; c < NH; ++c){
    float kv = ksh[c*64 + sl];
    float ewc = ewsh[c];
    #pragma unroll
    for (int i = 0; i < 6; ++i){
      int t = tp + i*8;
      if (t < TDEC){
        float v = kv + qsh[t*NH + c];
        float ex = __expf(2.0f*v);
        float rc = __builtin_amdgcn_rcpf(ex + 1.0f);
        acc[i] += ewc*(1.0f - 2.0f*rc);
      }
    }
  }
  #pragma unroll
  for (int i = 0; i < 6; ++i){
    int t = tp + i*8;
    if (t < TDEC) e[(b*TDEC + t)*SPAT + s0 + sl] = acc[i];
  }
}

// ---------------- attn_feat with fused softmax -------------------------------
__global__ __launch_bounds__(256) void k_attnf2(const float* __restrict__ feat,
    const float* __restrict__ e, float* __restrict__ attnf)
{
  int bid = blockIdx.x;                  // (b, tq(11), ch(2)): 352 blocks
  int ch = bid & 1; int rest = bid >> 1;
  int tq = rest % 11; int b = rest / 11;
  int tid = threadIdx.x;
  __shared__ __align__(16) float ash[4*SPAT];
  __shared__ float psh[4*4*64];
  __shared__ float sinv[4];
  for (int i = 0; i < 16; ++i){
    int e2 = i*256 + tid; int tt = e2 >> 10; int s = e2 & 1023;
    int t = tq*4 + tt;
    ash[e2] = (t < TDEC) ? e[(b*TDEC + t)*SPAT + s] : 0.f;
  }
  __syncthreads();
  {
    int w = tid >> 6; int l = tid & 63;    // wave w owns row w
    float* row = ash + w*SPAT;
    float vreg[16];
    float mx = -1e30f;
    #pragma unroll
    for (int j = 0; j < 16; ++j){ vreg[j] = row[l + j*64]; mx = fmaxf(mx, vreg[j]); }
    #pragma unroll
    for (int m = 1; m < 64; m <<= 1) mx = fmaxf(mx, __shfl_xor(mx, m));
    float sum = 0.f;
    #pragma unroll
    for (int j = 0; j < 16; ++j){
      float ev = __expf(vreg[j] - mx);
      row[l + j*64] = ev;
      sum += ev;
    }
    #pragma unroll
    for (int m = 1; m < 64; m <<= 1) sum += __shfl_xor(sum, m);
    if (l == 0) sinv[w] = 1.0f/sum;
  }
  __syncthreads();
  int cl = tid & 63; int sq = tid >> 6;
  const float* fp = feat + (b*NH + ch*64 + cl)*SPAT + sq*256;
  float acc[4] = {0.f,0.f,0.f,0.f};
  for (int i = 0; i < 64; ++i){
    float4 fv = *(const float4*)(fp + i*4);
    #pragma unroll
    for (int tt = 0; tt < 4; ++tt){
      const float* ar = ash + tt*SPAT + sq*256 + i*4;
      acc[tt] += fv.x*ar[0] + fv.y*ar[1] + fv.z*ar[2] + fv.w*ar[3];
    }
  }
  #pragma unroll
  for (int tt = 0; tt < 4; ++tt) psh[(sq*4 + tt)*64 + cl] = acc[tt];
  __syncthreads();
  {
    int tt = tid >> 6; int c2 = tid & 63;
    int t = tq*4 + tt;
    if (t < TDEC){
      float v = psh[(0*4 + tt)*64 + c2] + psh[(1*4 + tt)*64 + c2]
              + psh[(2*4 + tt)*64 + c2] + psh[(3*4 + tt)*64 + c2];
      attnf[(b*TDEC + t)*NH + ch*64 + c2] = v*sinv[tt];
    }
  }
}

// ---------------- fc via split-fp16 MFMA: out = attnf @ fcw^T + fcb ----------
__global__ __launch_bounds__(256) void k_fc2(const float* __restrict__ attnf,
    const uint4* __restrict__ fcwH, const uint4* __restrict__ fcwL,
    const float* __restrict__ fcb, float* __restrict__ out)
{
  int mf = blockIdx.x;                  // 0..40
  int ny = blockIdx.y;                  // 0..25
  int tid = threadIdx.x;
  int l = tid & 63, w = tid >> 6;
  half8 ah[4], al[4];
  const float* ap = attnf + (mf*16 + (l & 15))*NH + ((l >> 4) << 3);
  #pragma unroll
  for (int kf = 0; kf < 4; ++kf){
    float4 v0 = *(const float4*)(ap + kf*32);
    float4 v1 = *(const float4*)(ap + kf*32 + 4);
    float vv[8] = {v0.x, v0.y, v0.z, v0.w, v1.x, v1.y, v1.z, v1.w};
    half8 h, lo;
    #pragma unroll
    for (int j = 0; j < 8; ++j){
      h[j]  = (_Float16)vv[j];
      lo[j] = (_Float16)(vv[j] - (float)h[j]);
    }
    ah[kf] = h; al[kf] = lo;
  }
  #pragma unroll
  for (int i = 0; i < 4; ++i){
    int nf = ny*16 + w*4 + i;
    if (nf >= NFRAG) return;
    f32x4 acc{0.f,0.f,0.f,0.f};
    #pragma unroll
    for (int kf = 0; kf < 4; ++kf){
      uint4 bH = fcwH[(nf*4 + kf)*64 + l];
      uint4 bL = fcwL[(nf*4 + kf)*64 + l];
      half8 wh = __builtin_bit_cast(half8, bH);
      half8 wl = __builtin_bit_cast(half8, bL);
      acc = __builtin_amdgcn_mfma_f32_16x16x32_f16(ah[kf], wh, acc, 0, 0, 0);
      acc = __builtin_amdgcn_mfma_f32_16x16x32_f16(al[kf], wh, acc, 0, 0, 0);
      acc = __builtin_amdgcn_mfma_f32_16x16x32_f16(ah[kf], wl, acc, 0, 0, 0);
    }
    int n = nf*16 + (l & 15);
    if (n < NCLS){
      float bias = fcb[n];
      int mrow = mf*16 + ((l >> 4) << 2);
      #pragma unroll
      for (int q = 0; q < 4; ++q)
        out[(mrow + q)*NCLS + n] = acc[q] + bias;
    }
  }
}

// ============================================================================
extern "C" void kernel_launch(void* const* d_in, const int* in_sizes, int n_in,
                              void* d_out, int out_size, void* d_ws, size_t ws_size,
                              hipStream_t stream)
{
  (void)in_sizes; (void)n_in; (void)out_size; (void)ws_size;
  const float* x      = (const float*)d_in[0];
  const int*   tgt    = (const int*)  d_in[1];
  const float* conv0w = (const float*)d_in[2];
  const float* conv0b = (const float*)d_in[3];
  const float* bn0g   = (const float*)d_in[4];
  const float* bn0b   = (const float*)d_in[5];
  const float* bn0m   = (const float*)d_in[6];
  const float* bn0v   = (const float*)d_in[7];
  const float* dww    = (const float*)d_in[8];
  const float* dwb    = (const float*)d_in[9];
  const float* bn1g   = (const float*)d_in[10];
  const float* bn1b   = (const float*)d_in[11];
  const float* bn1m   = (const float*)d_in[12];
  const float* bn1v   = (const float*)d_in[13];
  const float* pww    = (const float*)d_in[14];
  const float* pwb    = (const float*)d_in[15];
  const float* bn2g   = (const float*)d_in[16];
  const float* bn2b   = (const float*)d_in[17];
  const float* bn2m   = (const float*)d_in[18];
  const float* bn2v   = (const float*)d_in[19];
  const float* encwih = (const float*)d_in[20];
  const float* encwhh = (const float*)d_in[21];
  const float* encbih = (const float*)d_in[22];
  const float* encbhh = (const float*)d_in[23];
  const float* decwih = (const float*)d_in[24];
  const float* decwhh = (const float*)d_in[25];
  const float* decbih = (const float*)d_in[26];
  const float* decbhh = (const float*)d_in[27];
  const float* emb    = (const float*)d_in[28];
  const float* qw     = (const float*)d_in[29];
  const float* qb0    = (const float*)d_in[30];
  const float* kw     = (const float*)d_in[31];
  const float* kb     = (const float*)d_in[32];
  const float* ew     = (const float*)d_in[33];
  const float* eb     = (const float*)d_in[34];
  const float* fcw    = (const float*)d_in[35];
  const float* fcb    = (const float*)d_in[36];

  float* ws    = (float*)d_ws;
  float* hbuf  = ws + 0;         // 2097152
  float* tbuf  = ws + 2097152;   // 2097152 (t; dead after k_pw -> ebuf alias)
  float* feat  = ws + 4194304;   // 2097152
  float* xp    = ws + 6291456;   // 393216
  float* indec = ws + 6684672;   // 41984
  float* xpd   = ws + 6726656;   // 125952
  float* ybuf  = ws + 6852608;   // 41984
  float* qbuf  = ws + 6894592;   // 83968
  float* attf  = ws + 6978560;   // 83968
  float* pwT   = ws + 7062528;   // 16384
  _Float16* kwA = (_Float16*)(ws + 7078912);   // 147456 halves
  unsigned* enc16 = (unsigned*)(ws + 7152640); // 6144 u32
  unsigned* dec16 = (unsigned*)(ws + 7158784); // 6144 u32
  _Float16* fcwH = (_Float16*)(ws + 7164928);  // 849920 halves
  _Float16* fcwL = (_Float16*)(ws + 7589888);  // 849920 halves
  // wihH/L in regions dead until k_xpd / dec-scan+k_q:
  _Float16* wihH = (_Float16*)(ws + 6726656);  // 196608 halves (xpd region)
  _Float16* wihL = (_Float16*)(ws + 6852608);  // 196608 halves (ybuf+qbuf region)
  float* kbuf  = hbuf;           // alias: h dead after k_dw
  float* ebuf  = tbuf;           // alias: t dead after k_pw (671744 floats)
  float* out   = (float*)d_out;

  hipLaunchKernelGGL(k_front,   dim3(6984),        dim3(256), 0, stream,
                     x, conv0w, conv0b, bn0g, bn0b, bn0m, bn0v, hbuf,
                     pww, pwT, kw, kwA, tgt, emb, indec,
                     encwhh, enc16, decwhh, dec16, encwih, wihH, wihL,
                     fcw, fcwH, fcwL);
  hipLaunchKernelGGL(k_dw,      dim3(8192),        dim3(256), 0, stream,
                     hbuf, dww, dwb, bn1g, bn1b, bn1m, bn1v, tbuf);
  hipLaunchKernelGGL(k_pw,      dim3(256),         dim3(512), 0, stream,
                     tbuf, pwT, pwb, bn2g, bn2b, bn2m, bn2v, feat);
  hipLaunchKernelGGL(k_encxp3,  dim3(512),         dim3(64), 0, stream,
                     feat, (const uint4*)wihH, (const uint4*)wihL, encbih, xp);
  hipLaunchKernelGGL(k_escan_conv, dim3(1040),     dim3(64), 0, stream,
                     xp, (const uint4*)enc16, encbhh, indec,
                     feat, (const uint4*)kwA, kb, kbuf);
  hipLaunchKernelGGL(k_xpd,     dim3(492),         dim3(256), 0, stream,
                     indec, decwih, decbih, xpd);
  hipLaunchKernelGGL((k_scan2<TDEC,true>), dim3(16), dim3(64), 0, stream,
                     xpd, (const uint4*)dec16, decbhh, ybuf);
  hipLaunchKernelGGL(k_q,       dim3(328),         dim3(256), 0, stream,
                     ybuf, qw, qb0, qbuf);
  hipLaunchKernelGGL(k_e3,      dim3(256),         dim3(512), 0, stream,
                     kbuf, qbuf, ew, eb, ebuf);
  hipLaunchKernelGGL(k_attnf2,  dim3(352),         dim3(256), 0, stream,
                     feat, ebuf, attf);
  hipLaunchKernelGGL(k_fc2,     dim3(41, 26),      dim3(256), 0, stream,
                     attf, (const uint4*)fcwH, (const uint4*)fcwL, fcb, out);
}

// Round 22
// 260.206 us; speedup vs baseline: 1.1422x; 1.1422x over previous
//
#include <hip/hip_runtime.h>
#include <hip/hip_bf16.h>

#define DEV __device__ __forceinline__

#define B_    16
#define T_    40
#define TDEC  41
#define NH    128
#define HF    8
#define WF    128
#define HID   64
#define G3    192
#define NCLS  6625
#define SPAT  1024
#define NFRAG 415          // ceil(6625/16)

typedef _Float16 half8 __attribute__((ext_vector_type(8)));
typedef _Float16 half2_ __attribute__((ext_vector_type(2)));
typedef float    f32x4 __attribute__((ext_vector_type(4)));
typedef float    f32x2 __attribute__((ext_vector_type(2)));

#if __has_builtin(__builtin_amdgcn_fdot2)
#define FDOT2(w,h,acc) __builtin_amdgcn_fdot2((w),(h),(acc),false)
#else
#define FDOT2(w,h,acc) ((acc) + (float)((w)[0])*(float)((h)[0]) + (float)((w)[1])*(float)((h)[1]))
#endif

DEV float sigmoidf_(float x){ return 1.0f/(1.0f + __expf(-x)); }
DEV float tanhf_(float x){ float e = __expf(2.0f*x); return 1.0f - 2.0f/(e + 1.0f); }
DEV float gelu_(float x){ return 0.5f*x*(1.0f + erff(x*0.70710678118654752f)); }
DEV float bnf_(float x, float g, float b, float m, float v){
  return (x - m)*rsqrtf(v + 1e-5f)*g + b;
}

// scan step macro (locals: w0q/w1q/w2q, b0..b2, hg, hsh16, xpb, x0a..x2c, outp, b, g)
#define SCAN_LOOP(STEPS, WRITE_ALL)                                            \
  for (int t = 0; t < (STEPS); ++t){                                           \
    float x0c = 0.f, x1c = 0.f, x2c = 0.f;                                     \
    if (t + 2 < (STEPS)){                                                      \
      const float* p = xpb + (t + 2)*G3 + g;                                   \
      x0c = p[0]; x1c = p[HID]; x2c = p[2*HID];                                \
    }                                                                          \
    const uint4* h4 = (const uint4*)hsh16;                                     \
    float a0 = b0, a1 = b1, a2 = b2;                                           \
    float d0 = 0.f, d1 = 0.f, d2 = 0.f;                                        \
    _Pragma("unroll")                                                          \
    for (int i = 0; i < 8; i += 2){                                            \
      uint4 hvA = h4[i], hvB = h4[i+1];                                        \
      DO4(hvA, i,   a0, a1, a2)                                                \
      DO4(hvB, i+1, d0, d1, d2)                                                \
    }                                                                          \
    float hp0 = a0 + d0;                                                       \
    float hp1 = a1 + d1;                                                       \
    float hp2 = a2 + d2;                                                       \
    float e0 = __expf(-(x0a + hp0));                                           \
    float r  = __builtin_amdgcn_rcpf(1.0f + e0);                               \
    float e1 = __expf(-(x1a + hp1));                                           \
    float z  = __builtin_amdgcn_rcpf(1.0f + e1);                               \
    float ag = x2a + r*hp2;                                                    \
    float ex = __expf(2.0f*ag);                                                \
    float n  = 1.0f - 2.0f*__builtin_amdgcn_rcpf(ex + 1.0f);                   \
    hg = z*(hg - n) + n;                                                       \
    if (WRITE_ALL) outp[(b*TDEC + t)*HID + g] = hg;                            \
    hsh16[g] = (_Float16)hg;                                                   \
    x0a = x0b; x1a = x1b; x2a = x2b;                                           \
    x0b = x0c; x1b = x1c; x2b = x2c;                                           \
  }

#define DO4(hv, wq, aa, bb, cc)                                                \
  { half2_ h0 = __builtin_bit_cast(half2_, hv.x);                              \
    half2_ h1 = __builtin_bit_cast(half2_, hv.y);                              \
    half2_ h2 = __builtin_bit_cast(half2_, hv.z);                              \
    half2_ h3 = __builtin_bit_cast(half2_, hv.w);                              \
    aa = FDOT2(__builtin_bit_cast(half2_, w0q[wq].x), h0, aa);                 \
    bb = FDOT2(__builtin_bit_cast(half2_, w1q[wq].x), h0, bb);                 \
    cc = FDOT2(__builtin_bit_cast(half2_, w2q[wq].x), h0, cc);                 \
    aa = FDOT2(__builtin_bit_cast(half2_, w0q[wq].y), h1, aa);                 \
    bb = FDOT2(__builtin_bit_cast(half2_, w1q[wq].y), h1, bb);                 \
    cc = FDOT2(__builtin_bit_cast(half2_, w2q[wq].y), h1, cc);                 \
    aa = FDOT2(__builtin_bit_cast(half2_, w0q[wq].z), h2, aa);                 \
    bb = FDOT2(__builtin_bit_cast(half2_, w1q[wq].z), h2, bb);                 \
    cc = FDOT2(__builtin_bit_cast(half2_, w2q[wq].z), h2, cc);                 \
    aa = FDOT2(__builtin_bit_cast(half2_, w0q[wq].w), h3, aa);                 \
    bb = FDOT2(__builtin_bit_cast(half2_, w1q[wq].w), h3, bb);                 \
    cc = FDOT2(__builtin_bit_cast(half2_, w2q[wq].w), h3, cc); }

// ---------------- FRONT: conv0 | misc preps | fcprep (merged, independent) ---
__global__ __launch_bounds__(256) void k_front(
    const float* __restrict__ x, const float* __restrict__ w,
    const float* __restrict__ bias, const float* __restrict__ bng,
    const float* __restrict__ bnb, const float* __restrict__ bnm,
    const float* __restrict__ bnv, float* __restrict__ h,
    const float* __restrict__ pw, float* __restrict__ pwT,
    const float* __restrict__ kw, _Float16* __restrict__ kwA,
    const int* __restrict__ tgt, const float* __restrict__ emb,
    float* __restrict__ indec,
    const float* __restrict__ encwhh, unsigned* __restrict__ enc16,
    const float* __restrict__ decwhh, unsigned* __restrict__ dec16,
    const float* __restrict__ wih, _Float16* __restrict__ wihH,
    _Float16* __restrict__ wihL,
    const float* __restrict__ fcw, _Float16* __restrict__ fcwH,
    _Float16* __restrict__ fcwL)
{
  int bid = blockIdx.x;
  if (bid < 2048){
    int tid = bid*256 + threadIdx.x;
    int ow = tid & 127;
    int oh = (tid >> 7) & 7;
    int c4 = (tid >> 10) & 31;
    int b  = tid >> 15;
    float acc[4] = {0.f,0.f,0.f,0.f};
    int xbase = ((b*3)*32 + oh*4)*512 + ow*4;
    for (int ci = 0; ci < 3; ++ci){
      #pragma unroll
      for (int kh = 0; kh < 4; ++kh){
        float4 xv = *(const float4*)(x + xbase + ci*(32*512) + kh*512);
        #pragma unroll
        for (int cc = 0; cc < 4; ++cc){
          int co = c4*4 + cc;
          const float* wp = w + ((co*3 + ci)*4 + kh)*4;
          acc[cc] += xv.x*wp[0] + xv.y*wp[1] + xv.z*wp[2] + xv.w*wp[3];
        }
      }
    }
    #pragma unroll
    for (int cc = 0; cc < 4; ++cc){
      int co = c4*4 + cc;
      float v = acc[cc] + bias[co];
      v = bnf_(v, bng[co], bnb[co], bnm[co], bnv[co]);
      h[((b*NH + co)*HF + oh)*WF + ow] = gelu_(v);
    }
  } else if (bid < 3664){
    int mbid = bid - 2048;
    if (mbid < 64){
      int tid = mbid*256 + threadIdx.x;      // 16384
      int ci = tid & 127; int co = tid >> 7;
      pwT[ci*128 + co] = pw[16384 + co*128 + ci];
    } else if (mbid < 640){
      int tid = (mbid - 64)*256 + threadIdx.x;   // 147456
      int j = tid & 7;
      int l = (tid >> 3) & 63;
      int f = (tid >> 9) & 7;
      int s = tid >> 12;
      int co = f*16 + (l & 15);
      int k  = s*32 + ((l >> 4) << 3) + j;
      int r  = k >> 7;
      int ci = k & 127;
      kwA[tid] = (_Float16)kw[(co*128 + ci)*9 + r];
    } else if (mbid < 800){
      int tid = (mbid - 640)*256 + threadIdx.x;  // 40960
      if (tid >= B_*T_*HID) return;
      int j = tid & 63; int rest = tid >> 6;
      int t = rest % T_; int b = rest / T_;
      int cls = tgt[b*T_ + t];
      indec[(b*TDEC + 1 + t)*HID + j] = emb[cls*HID + j];
    } else if (mbid < 848){
      int seg = mbid - 800;                      // 0..47 (24 enc, 24 dec)
      const float* src = (seg < 24) ? encwhh : decwhh;
      unsigned* dst    = (seg < 24) ? enc16   : dec16;
      int tid = (seg % 24)*256 + threadIdx.x;   // 6144
      int r = tid >> 5; int k2 = tid & 31;
      half2_ hv;
      hv[0] = (_Float16)src[r*HID + 2*k2];
      hv[1] = (_Float16)src[r*HID + 2*k2 + 1];
      dst[tid] = __builtin_bit_cast(unsigned, hv);
    } else {
      int tid = (mbid - 848)*256 + threadIdx.x;  // 196608
      if (tid >= 12*32*64*8) return;
      int j  = tid & 7;
      int l  = (tid >> 3) & 63;
      int kf = (tid >> 9) & 31;
      int nf = tid >> 14;
      int n = nf*16 + (l & 15);
      int k = kf*32 + ((l >> 4) << 3) + j;
      float v = wih[n*1024 + k];
      _Float16 hi = (_Float16)v;
      wihH[tid] = hi;
      wihL[tid] = (_Float16)(v - (float)hi);
    }
  } else {
    int tid = (bid - 3664)*256 + threadIdx.x;   // 849920
    if (tid >= NFRAG*4*64*8) return;
    int j  = tid & 7;
    int l  = (tid >> 3) & 63;
    int kf = (tid >> 9) & 3;
    int nf = tid >> 11;
    int n = nf*16 + (l & 15);
    int k = kf*32 + ((l >> 4) << 3) + j;
    float v = (n < NCLS) ? fcw[n*NH + k] : 0.f;
    _Float16 hi = (_Float16)v;
    fcwH[tid] = hi;
    fcwL[tid] = (_Float16)(v - (float)hi);
  }
}

// ---------------- depthwise 3x3 (blk idx 1) + BN + GELU + residual -> t -------
__global__ __launch_bounds__(256) void k_dw(const float* __restrict__ h,
    const float* __restrict__ dww, const float* __restrict__ dwb,
    const float* __restrict__ g1, const float* __restrict__ b1,
    const float* __restrict__ m1, const float* __restrict__ v1,
    float* __restrict__ t)
{
  int tid = blockIdx.x*256 + threadIdx.x;   // 2097152
  int ow = tid & 127;
  int oh = (tid >> 7) & 7;
  int c  = (tid >> 10) & 127;
  int b  = tid >> 17;
  const float* wp = dww + NH*9 + c*9;       // block index 1
  const float* hp = h + ((b*NH + c)*HF)*WF;
  float acc = 0.f;
  #pragma unroll
  for (int kh = 0; kh < 3; ++kh){
    int ih = oh + kh - 1;
    if (ih < 0 || ih >= HF) continue;
    #pragma unroll
    for (int kw = 0; kw < 3; ++kw){
      int iw = ow + kw - 1;
      if (iw < 0 || iw >= WF) continue;
      acc += hp[ih*WF + iw]*wp[kh*3 + kw];
    }
  }
  float val = acc + dwb[NH + c];
  val = bnf_(val, g1[NH + c], b1[NH + c], m1[NH + c], v1[NH + c]);
  t[tid] = hp[oh*WF + ow] + gelu_(val);
}

// ---------------- pointwise 128x128 (blk idx 1) + BN + GELU -> feat ----------
__global__ __launch_bounds__(512) void k_pw(const float* __restrict__ t,
    const float* __restrict__ pwT, const float* __restrict__ pwb,
    const float* __restrict__ g2, const float* __restrict__ b2,
    const float* __restrict__ m2, const float* __restrict__ v2,
    float* __restrict__ feat)
{
  int bid = blockIdx.x;                     // (b, oh, whalf): 256 blocks
  int wh = bid & 1; int oh = (bid >> 1) & 7; int b = bid >> 4;
  int w0 = wh*64;
  int tid = threadIdx.x;
  __shared__ __align__(16) float tile[128*64];
  for (int i = 0; i < 16; ++i){
    int e = i*512 + tid; int ci = e >> 6; int wloc = e & 63;
    tile[ci*64 + wloc] = t[((b*NH + ci)*HF + oh)*WF + w0 + wloc];
  }
  __syncthreads();
  int co = tid & 127; int wq = tid >> 7;
  float acc[16];
  #pragma unroll
  for (int i = 0; i < 16; ++i) acc[i] = 0.f;
  for (int ci = 0; ci < 128; ++ci){
    float wt = pwT[ci*128 + co];
    const float4* tp = (const float4*)(tile + ci*64 + wq*16);
    #pragma unroll
    for (int j = 0; j < 4; ++j){
      float4 tv = tp[j];
      acc[j*4+0] += tv.x*wt; acc[j*4+1] += tv.y*wt;
      acc[j*4+2] += tv.z*wt; acc[j*4+3] += tv.w*wt;
    }
  }
  float bb = pwb[128 + co];
  float gg = g2[128 + co], bc = b2[128 + co], mm = m2[128 + co], vv = v2[128 + co];
  float* op = feat + ((b*NH + co)*HF + oh)*WF + w0 + wq*16;
  #pragma unroll
  for (int i = 0; i < 16; ++i){
    float v = bnf_(acc[i] + bb, gg, bc, mm, vv);
    op[i] = gelu_(v);
  }
}

// ---------------- enc xp via split-fp16 MFMA, 512 waves ----------------------
__global__ __launch_bounds__(64) void k_encxp3(const float* __restrict__ feat,
    const uint4* __restrict__ wihH, const uint4* __restrict__ wihL,
    const float* __restrict__ bih, float* __restrict__ xp)
{
  int bid = blockIdx.x;
  int mf = bid & 127;              // b = mf>>3, w-chunk = mf&7
  int ny = bid >> 7;               // 0..3 -> nf = ny*3 + {0,1,2}
  int l  = threadIdx.x;
  int b  = mf >> 3, wc = mf & 7;
  int m_w = wc*16 + (l & 15);
  f32x4 acc0{0.f,0.f,0.f,0.f}, acc1{0.f,0.f,0.f,0.f}, acc2{0.f,0.f,0.f,0.f};
  int nf0 = ny*3;
  for (int kf = 0; kf < 32; ++kf){
    int ci = kf*4 + (l >> 4);
    const float* ap = feat + ((b*NH + ci)*HF)*WF + m_w;
    float av[8];
    #pragma unroll
    for (int j = 0; j < 8; ++j) av[j] = ap[j*WF];
    half8 ah, al;
    #pragma unroll
    for (int j = 0; j < 8; ++j){
      ah[j] = (_Float16)av[j];
      al[j] = (_Float16)(av[j] - (float)ah[j]);
    }
    uint4 bH0 = wihH[((nf0+0)*32 + kf)*64 + l];
    uint4 bL0 = wihL[((nf0+0)*32 + kf)*64 + l];
    uint4 bH1 = wihH[((nf0+1)*32 + kf)*64 + l];
    uint4 bL1 = wihL[((nf0+1)*32 + kf)*64 + l];
    uint4 bH2 = wihH[((nf0+2)*32 + kf)*64 + l];
    uint4 bL2 = wihL[((nf0+2)*32 + kf)*64 + l];
    #define ACCUM(accv, bH, bL) {                                              \
      half8 wh = __builtin_bit_cast(half8, bH);                                \
      half8 wl = __builtin_bit_cast(half8, bL);                                \
      accv = __builtin_amdgcn_mfma_f32_16x16x32_f16(ah, wh, accv, 0, 0, 0);    \
      accv = __builtin_amdgcn_mfma_f32_16x16x32_f16(al, wh, accv, 0, 0, 0);    \
      accv = __builtin_amdgcn_mfma_f32_16x16x32_f16(ah, wl, accv, 0, 0, 0);    \
    }
    ACCUM(acc0, bH0, bL0)
    ACCUM(acc1, bH1, bL1)
    ACCUM(acc2, bH2, bL2)
    #undef ACCUM
  }
  int mbase = b*WF + wc*16 + ((l >> 4) << 2);
  #pragma unroll
  for (int i = 0; i < 3; ++i){
    f32x4 a = (i == 0) ? acc0 : (i == 1) ? acc1 : acc2;
    int n = (nf0 + i)*16 + (l & 15);
    float bias = bih[n];
    #pragma unroll
    for (int q = 0; q < 4; ++q)
      xp[(mbase + q)*G3 + n] = a[q] + bias;
  }
}

// ---------------- standalone dec scan (fp16 weights + fdot2) -----------------
template<int STEPS, bool WRITE_ALL>
__global__ __attribute__((amdgpu_waves_per_eu(1, 1))) __launch_bounds__(64)
void k_scan2(const float* __restrict__ xp, const uint4* __restrict__ whh16,
             const float* __restrict__ bhh, float* __restrict__ outp)
{
  __shared__ __align__(16) _Float16 hsh16[HID];
  int g = threadIdx.x;
  int b = blockIdx.x;
  uint4 w0q[8], w1q[8], w2q[8];
  const uint4* q0 = whh16 + g*8;
  const uint4* q1 = whh16 + (HID + g)*8;
  const uint4* q2 = whh16 + (2*HID + g)*8;
  #pragma unroll
  for (int k = 0; k < 8; ++k){ w0q[k] = q0[k]; w1q[k] = q1[k]; w2q[k] = q2[k]; }
  float b0 = bhh[g], b1 = bhh[HID + g], b2 = bhh[2*HID + g];
  float hg = 0.f;
  hsh16[g] = (_Float16)0.f;
  const float* xpb = xp + b*STEPS*G3;
  float x0a = xpb[g], x1a = xpb[HID + g], x2a = xpb[2*HID + g];
  float x0b = 0.f, x1b = 0.f, x2b = 0.f;
  if (STEPS > 1){
    const float* p = xpb + G3 + g;
    x0b = p[0]; x1b = p[HID]; x2b = p[2*HID];
  }
  SCAN_LOOP(STEPS, WRITE_ALL)
  if (!WRITE_ALL) outp[(b*TDEC)*HID + g] = hg;
}

// ---------------- MERGED: enc scan (blocks 0-15) + kconv (16-4111) -----------
// R18/R20 conv body (fp32 coalesced gather + cvt): measured 63.3us merged.
__global__ __launch_bounds__(64) void k_escan_conv(
    const float* __restrict__ xp, const uint4* __restrict__ whh16,
    const float* __restrict__ bhh, float* __restrict__ outp,
    const float* __restrict__ feat, const uint4* __restrict__ kwA4,
    const float* __restrict__ kb, float* __restrict__ ko)
{
  __shared__ __align__(16) _Float16 hsh16[HID];
  int bigid = blockIdx.x;
  if (bigid < 16){
    __builtin_amdgcn_s_setprio(3);
    int g = threadIdx.x;
    int b = bigid;
    uint4 w0q[8], w1q[8], w2q[8];
    const uint4* q0 = whh16 + g*8;
    const uint4* q1 = whh16 + (HID + g)*8;
    const uint4* q2 = whh16 + (2*HID + g)*8;
    #pragma unroll
    for (int k = 0; k < 8; ++k){ w0q[k] = q0[k]; w1q[k] = q1[k]; w2q[k] = q2[k]; }
    float b0 = bhh[g], b1 = bhh[HID + g], b2 = bhh[2*HID + g];
    float hg = 0.f;
    hsh16[g] = (_Float16)0.f;
    const float* xpb = xp + b*WF*G3;
    float x0a = xpb[g], x1a = xpb[HID + g], x2a = xpb[2*HID + g];
    float x0b = 0.f, x1b = 0.f, x2b = 0.f;
    {
      const float* p = xpb + G3 + g;
      x0b = p[0]; x1b = p[HID]; x2b = p[2*HID];
    }
    SCAN_LOOP(WF, false)
    outp[(b*TDEC)*HID + g] = hg;
    __builtin_amdgcn_s_setprio(0);
    return;
  }
  int bid = bigid - 16;
  int b  = ((bid & 7) << 1) | ((bid >> 3) & 1);   // XCD-aware batch pair
  int mq = (bid >> 4) & 3;
  int cs = (bid >> 6) & 3;
  int wq = (bid >> 8) & 1;
  int oh = (bid >> 9) & 7;
  int l  = threadIdx.x;
  int w0 = wq*64 + mq*16;
  int iwb = w0 + (l & 15);
  int cib = (l >> 4) << 3;

  f32x4 acc0{0.f,0.f,0.f,0.f}, acc1{0.f,0.f,0.f,0.f};
  uint4 a0A, a0B, a1A, a1B;
  float b0v[8], b1v[8];

  #define ISS(s, aX, aY, bvv) {                                               \
    aX = kwA4[(s)*512 + cs*128 + l];                                          \
    aY = kwA4[(s)*512 + cs*128 + 64 + l];                                     \
    int r = (s) >> 2; int dh = r/3 - 1; int dw2 = r%3 - 1;                    \
    int ci0 = ((s) & 3) << 5;                                                 \
    int ih = oh + dh; int iw = iwb + dw2;                                     \
    bool ok = (ih >= 0) & (ih < HF) & (iw >= 0) & (iw < WF);                  \
    const float* fp = feat + ((b*NH + ci0 + cib)*HF + ih)*WF + iw;            \
    _Pragma("unroll")                                                         \
    for (int jj = 0; jj < 8; ++jj) bvv[jj] = ok ? fp[jj*(HF*WF)] : 0.f;       \
  }
  #define CMP(aX, aY, bvv) {                                                  \
    half8 bf;                                                                 \
    _Pragma("unroll")                                                         \
    for (int jj = 0; jj < 8; ++jj) bf[jj] = (_Float16)bvv[jj];                \
    half8 af0 = __builtin_bit_cast(half8, aX);                                \
    half8 af1 = __builtin_bit_cast(half8, aY);                                \
    acc0 = __builtin_amdgcn_mfma_f32_16x16x32_f16(af0, bf, acc0, 0, 0, 0);    \
    acc1 = __builtin_amdgcn_mfma_f32_16x16x32_f16(af1, bf, acc1, 0, 0, 0);    \
  }

  ISS(0, a0A, a0B, b0v);
  for (int s = 0; s < 36; s += 2){
    if (s + 1 < 36) ISS(s + 1, a1A, a1B, b1v);
    CMP(a0A, a0B, b0v);
    if (s + 2 < 36) ISS(s + 2, a0A, a0B, b0v);
    if (s + 1 < 36) CMP(a1A, a1B, b1v);
  }
  #undef ISS
  #undef CMP

  int m = w0 + (l & 15);
  #pragma unroll
  for (int q = 0; q < 4; ++q){
    int co0 = cs*32 + ((l >> 4) << 2) + q;
    int co1 = co0 + 16;
    ko[((b*NH + co0)*HF + oh)*WF + m] = acc0[q] + kb[co0];
    ko[((b*NH + co1)*HF + oh)*WF + m] = acc1[q] + kb[co1];
  }
}

// ---------------- dec xp: (656x64)@(192x64)^T + bih --------------------------
__global__ void k_xpd(const float* __restrict__ indec, const float* __restrict__ wih,
                      const float* __restrict__ bih, float* __restrict__ xpd)
{
  int tid = blockIdx.x*256 + threadIdx.x;   // 125952
  if (tid >= B_*TDEC*G3) return;
  int g = tid % G3; int bt = tid / G3;
  const float4* r4 = (const float4*)(indec + bt*HID);
  const float4* w4 = (const float4*)(wih + g*HID);
  float acc = bih[g];
  #pragma unroll
  for (int j = 0; j < 16; ++j){
    float4 rv = r4[j], wv = w4[j];
    acc += rv.x*wv.x + rv.y*wv.y + rv.z*wv.z + rv.w*wv.w;
  }
  xpd[tid] = acc;
}

// ---------------- q = y @ q_w^T + q_b ---------------------------------------
__global__ void k_q(const float* __restrict__ y, const float* __restrict__ qw,
                    const float* __restrict__ qb0, float* __restrict__ q)
{
  int tid = blockIdx.x*256 + threadIdx.x;   // 83968
  if (tid >= B_*TDEC*NH) return;
  int co = tid & 127; int bt = tid >> 7;
  const float4* r4 = (const float4*)(y + bt*HID);
  const float4* w4 = (const float4*)(qw + co*HID);
  float acc = qb0[co];
  #pragma unroll
  for (int j = 0; j < 16; ++j){
    float4 rv = r4[j], wv = w4[j];
    acc += rv.x*wv.x + rv.y*wv.y + rv.z*wv.z + rv.w*wv.w;
  }
  q[tid] = acc;
}

// ---------------- e[b,t,s]: c-outer/t-inner, kv read once per c --------------
__global__ __launch_bounds__(512) void k_e3(const float* __restrict__ k,
    const float* __restrict__ q, const float* __restrict__ ew,
    const float* __restrict__ eb, float* __restrict__ e)
{
  int bid = blockIdx.x;                 // 256 blocks: (b, st)
  int st = bid & 15; int b = bid >> 4;
  int s0 = st*64;
  int tid = threadIdx.x;
  __shared__ float ksh[NH*64];          // 32 KB: k[b, c, s0..s0+63]
  __shared__ float qsh[TDEC*NH];        // 21 KB: q[b, :, :]
  __shared__ float ewsh[NH];
  #pragma unroll
  for (int i = 0; i < 16; ++i){
    int e2 = i*512 + tid; int c = e2 >> 6; int j = e2 & 63;
    ksh[e2] = k[(b*NH + c)*SPAT + s0 + j];
  }
  #pragma unroll
  for (int i = 0; i < 11; ++i){
    int e2 = i*512 + tid;
    if (e2 < TDEC*NH) qsh[e2] = q[b*TDEC*NH + e2];
  }
  if (tid < NH) ewsh[tid] = ew[tid];
  __syncthreads();
  int sl = tid & 63; int tp = tid >> 6;   // 8 t-groups
  float ebv = eb[0];
  float acc[6] = {ebv, ebv, ebv, ebv, ebv, ebv};
  #pragma unroll 2
  for (int c = 0; c < NH; ++c){
    float kv = ksh[c*64 + sl];
    float ewc = ewsh[c];
    #pragma unroll
    for (int i = 0; i < 6; ++i){
      int t = tp + i*8;
      if (t < TDEC){
        float v = kv + qsh[t*NH + c];
        float ex = __expf(2.0f*v);
        float rc = __builtin_amdgcn_rcpf(ex + 1.0f);
        acc[i] += ewc*(1.0f - 2.0f*rc);
      }
    }
  }
  #pragma unroll
  for (int i = 0; i < 6; ++i){
    int t = tp + i*8;
    if (t < TDEC) e[(b*TDEC + t)*SPAT + s0 + sl] = acc[i];
  }
}

// ---------------- attn_feat with fused softmax -------------------------------
__global__ __launch_bounds__(256) void k_attnf2(const float* __restrict__ feat,
    const float* __restrict__ e, float* __restrict__ attnf)
{
  int bid = blockIdx.x;                  // (b, tq(11), ch(2)): 352 blocks
  int ch = bid & 1; int rest = bid >> 1;
  int tq = rest % 11; int b = rest / 11;
  int tid = threadIdx.x;
  __shared__ __align__(16) float ash[4*SPAT];
  __shared__ float psh[4*4*64];
  __shared__ float sinv[4];
  for (int i = 0; i < 16; ++i){
    int e2 = i*256 + tid; int tt = e2 >> 10; int s = e2 & 1023;
    int t = tq*4 + tt;
    ash[e2] = (t < TDEC) ? e[(b*TDEC + t)*SPAT + s] : 0.f;
  }
  __syncthreads();
  {
    int w = tid >> 6; int l = tid & 63;    // wave w owns row w
    float* row = ash + w*SPAT;
    float vreg[16];
    float mx = -1e30f;
    #pragma unroll
    for (int j = 0; j < 16; ++j){ vreg[j] = row[l + j*64]; mx = fmaxf(mx, vreg[j]); }
    #pragma unroll
    for (int m = 1; m < 64; m <<= 1) mx = fmaxf(mx, __shfl_xor(mx, m));
    float sum = 0.f;
    #pragma unroll
    for (int j = 0; j < 16; ++j){
      float ev = __expf(vreg[j] - mx);
      row[l + j*64] = ev;
      sum += ev;
    }
    #pragma unroll
    for (int m = 1; m < 64; m <<= 1) sum += __shfl_xor(sum, m);
    if (l == 0) sinv[w] = 1.0f/sum;
  }
  __syncthreads();
  int cl = tid & 63; int sq = tid >> 6;
  const float* fp = feat + (b*NH + ch*64 + cl)*SPAT + sq*256;
  float acc[4] = {0.f,0.f,0.f,0.f};
  for (int i = 0; i < 64; ++i){
    float4 fv = *(const float4*)(fp + i*4);
    #pragma unroll
    for (int tt = 0; tt < 4; ++tt){
      const float* ar = ash + tt*SPAT + sq*256 + i*4;
      acc[tt] += fv.x*ar[0] + fv.y*ar[1] + fv.z*ar[2] + fv.w*ar[3];
    }
  }
  #pragma unroll
  for (int tt = 0; tt < 4; ++tt) psh[(sq*4 + tt)*64 + cl] = acc[tt];
  __syncthreads();
  {
    int tt = tid >> 6; int c2 = tid & 63;
    int t = tq*4 + tt;
    if (t < TDEC){
      float v = psh[(0*4 + tt)*64 + c2] + psh[(1*4 + tt)*64 + c2]
              + psh[(2*4 + tt)*64 + c2] + psh[(3*4 + tt)*64 + c2];
      attnf[(b*TDEC + t)*NH + ch*64 + c2] = v*sinv[tt];
    }
  }
}

// ---------------- fc via split-fp16 MFMA: out = attnf @ fcw^T + fcb ----------
__global__ __launch_bounds__(256) void k_fc2(const float* __restrict__ attnf,
    const uint4* __restrict__ fcwH, const uint4* __restrict__ fcwL,
    const float* __restrict__ fcb, float* __restrict__ out)
{
  int mf = blockIdx.x;                  // 0..40
  int ny = blockIdx.y;                  // 0..25
  int tid = threadIdx.x;
  int l = tid & 63, w = tid >> 6;
  half8 ah[4], al[4];
  const float* ap = attnf + (mf*16 + (l & 15))*NH + ((l >> 4) << 3);
  #pragma unroll
  for (int kf = 0; kf < 4; ++kf){
    float4 v0 = *(const float4*)(ap + kf*32);
    float4 v1 = *(const float4*)(ap + kf*32 + 4);
    float vv[8] = {v0.x, v0.y, v0.z, v0.w, v1.x, v1.y, v1.z, v1.w};
    half8 h, lo;
    #pragma unroll
    for (int j = 0; j < 8; ++j){
      h[j]  = (_Float16)vv[j];
      lo[j] = (_Float16)(vv[j] - (float)h[j]);
    }
    ah[kf] = h; al[kf] = lo;
  }
  #pragma unroll
  for (int i = 0; i < 4; ++i){
    int nf = ny*16 + w*4 + i;
    if (nf >= NFRAG) return;
    f32x4 acc{0.f,0.f,0.f,0.f};
    #pragma unroll
    for (int kf = 0; kf < 4; ++kf){
      uint4 bH = fcwH[(nf*4 + kf)*64 + l];
      uint4 bL = fcwL[(nf*4 + kf)*64 + l];
      half8 wh = __builtin_bit_cast(half8, bH);
      half8 wl = __builtin_bit_cast(half8, bL);
      acc = __builtin_amdgcn_mfma_f32_16x16x32_f16(ah[kf], wh, acc, 0, 0, 0);
      acc = __builtin_amdgcn_mfma_f32_16x16x32_f16(al[kf], wh, acc, 0, 0, 0);
      acc = __builtin_amdgcn_mfma_f32_16x16x32_f16(ah[kf], wl, acc, 0, 0, 0);
    }
    int n = nf*16 + (l & 15);
    if (n < NCLS){
      float bias = fcb[n];
      int mrow = mf*16 + ((l >> 4) << 2);
      #pragma unroll
      for (int q = 0; q < 4; ++q)
        out[(mrow + q)*NCLS + n] = acc[q] + bias;
    }
  }
}

// ============================================================================
extern "C" void kernel_launch(void* const* d_in, const int* in_sizes, int n_in,
                              void* d_out, int out_size, void* d_ws, size_t ws_size,
                              hipStream_t stream)
{
  (void)in_sizes; (void)n_in; (void)out_size; (void)ws_size;
  const float* x      = (const float*)d_in[0];
  const int*   tgt    = (const int*)  d_in[1];
  const float* conv0w = (const float*)d_in[2];
  const float* conv0b = (const float*)d_in[3];
  const float* bn0g   = (const float*)d_in[4];
  const float* bn0b   = (const float*)d_in[5];
  const float* bn0m   = (const float*)d_in[6];
  const float* bn0v   = (const float*)d_in[7];
  const float* dww    = (const float*)d_in[8];
  const float* dwb    = (const float*)d_in[9];
  const float* bn1g   = (const float*)d_in[10];
  const float* bn1b   = (const float*)d_in[11];
  const float* bn1m   = (const float*)d_in[12];
  const float* bn1v   = (const float*)d_in[13];
  const float* pww    = (const float*)d_in[14];
  const float* pwb    = (const float*)d_in[15];
  const float* bn2g   = (const float*)d_in[16];
  const float* bn2b   = (const float*)d_in[17];
  const float* bn2m   = (const float*)d_in[18];
  const float* bn2v   = (const float*)d_in[19];
  const float* encwih = (const float*)d_in[20];
  const float* encwhh = (const float*)d_in[21];
  const float* encbih = (const float*)d_in[22];
  const float* encbhh = (const float*)d_in[23];
  const float* decwih = (const float*)d_in[24];
  const float* decwhh = (const float*)d_in[25];
  const float* decbih = (const float*)d_in[26];
  const float* decbhh = (const float*)d_in[27];
  const float* emb    = (const float*)d_in[28];
  const float* qw     = (const float*)d_in[29];
  const float* qb0    = (const float*)d_in[30];
  const float* kw     = (const float*)d_in[31];
  const float* kb     = (const float*)d_in[32];
  const float* ew     = (const float*)d_in[33];
  const float* eb     = (const float*)d_in[34];
  const float* fcw    = (const float*)d_in[35];
  const float* fcb    = (const float*)d_in[36];

  float* ws    = (float*)d_ws;
  float* hbuf  = ws + 0;         // 2097152
  float* tbuf  = ws + 2097152;   // 2097152 (t; dead after k_pw -> ebuf alias)
  float* feat  = ws + 4194304;   // 2097152
  float* xp    = ws + 6291456;   // 393216
  float* indec = ws + 6684672;   // 41984
  float* xpd   = ws + 6726656;   // 125952
  float* ybuf  = ws + 6852608;   // 41984
  float* qbuf  = ws + 6894592;   // 83968
  float* attf  = ws + 6978560;   // 83968
  float* pwT   = ws + 7062528;   // 16384
  _Float16* kwA = (_Float16*)(ws + 7078912);   // 147456 halves
  unsigned* enc16 = (unsigned*)(ws + 7152640); // 6144 u32
  unsigned* dec16 = (unsigned*)(ws + 7158784); // 6144 u32
  _Float16* fcwH = (_Float16*)(ws + 7164928);  // 849920 halves
  _Float16* fcwL = (_Float16*)(ws + 7589888);  // 849920 halves
  // wihH/L in regions dead until k_xpd / dec-scan+k_q:
  _Float16* wihH = (_Float16*)(ws + 6726656);  // 196608 halves (xpd region)
  _Float16* wihL = (_Float16*)(ws + 6852608);  // 196608 halves (ybuf+qbuf region)
  float* kbuf  = hbuf;           // alias: h dead after k_dw
  float* ebuf  = tbuf;           // alias: t dead after k_pw (671744 floats)
  float* out   = (float*)d_out;

  hipLaunchKernelGGL(k_front,   dim3(6984),        dim3(256), 0, stream,
                     x, conv0w, conv0b, bn0g, bn0b, bn0m, bn0v, hbuf,
                     pww, pwT, kw, kwA, tgt, emb, indec,
                     encwhh, enc16, decwhh, dec16, encwih, wihH, wihL,
                     fcw, fcwH, fcwL);
  hipLaunchKernelGGL(k_dw,      dim3(8192),        dim3(256), 0, stream,
                     hbuf, dww, dwb, bn1g, bn1b, bn1m, bn1v, tbuf);
  hipLaunchKernelGGL(k_pw,      dim3(256),         dim3(512), 0, stream,
                     tbuf, pwT, pwb, bn2g, bn2b, bn2m, bn2v, feat);
  hipLaunchKernelGGL(k_encxp3,  dim3(512),         dim3(64), 0, stream,
                     feat, (const uint4*)wihH, (const uint4*)wihL, encbih, xp);
  hipLaunchKernelGGL(k_escan_conv, dim3(4112),     dim3(64), 0, stream,
                     xp, (const uint4*)enc16, encbhh, indec,
                     feat, (const uint4*)kwA, kb, kbuf);
  hipLaunchKernelGGL(k_xpd,     dim3(492),         dim3(256), 0, stream,
                     indec, decwih, decbih, xpd);
  hipLaunchKernelGGL((k_scan2<TDEC,true>), dim3(16), dim3(64), 0, stream,
                     xpd, (const uint4*)dec16, decbhh, ybuf);
  hipLaunchKernelGGL(k_q,       dim3(328),         dim3(256), 0, stream,
                     ybuf, qw, qb0, qbuf);
  hipLaunchKernelGGL(k_e3,      dim3(256),         dim3(512), 0, stream,
                     kbuf, qbuf, ew, eb, ebuf);
  hipLaunchKernelGGL(k_attnf2,  dim3(352),         dim3(256), 0, stream,
                     feat, ebuf, attf);
  hipLaunchKernelGGL(k_fc2,     dim3(41, 26),      dim3(256), 0, stream,
                     attf, (const uint4*)fcwH, (const uint4*)fcwL, fcb, out);
}